// Round 5
// baseline (696.586 us; speedup 1.0000x reference)
//
#include <hip/hip_runtime.h>
#include <hip/hip_bf16.h>

// GCN layer: N=100000, E=1600000, IN=256, OUT=32, fp32.
// Bucketed-LDS pipeline. R4 lesson: bucket_agg was GRID-occupancy-limited
// (782 blocks x 4 waves = 12 waves/CU max). R5: 1024-thr agg blocks ->
// 2 blocks/CU x 16 waves = 32 waves/CU; ~512 outstanding gathers/CU.
//   1) degree_kernel: cnt_out[src]++, cnt_in[dst]++, per-block bucket hist
//   2) gemm_kernel:   h = (feat * out_deg^-0.5) @ W   (R=8 x C=4 per thread)
//   3) bucket_scan:   exclusive scan of 1024 bucket counts
//   4) partition_kernel: LDS counting sort -> pairs[] grouped by dst-bucket
//      (packed u32: src[16:0] | dstlow[23:17]); coalesced segment flush
//   5) bucket_agg_kernel: 782 blocks x 1024 thr, 16KB LDS acc[128][32]
//      (bank=lane, conflict-free), 32 groups x unroll 8; fused epilogue
// Fallback: float-atomic aggregate if ws too small or N >= 2^17.

#define IN_F 256
#define OUT_F 32

// gemm tiling
#define G_ROWS 256
#define G_KT 32
#define G_KPAD 36

// buckets
#define BSHIFT 7
#define BNODES 128
#define NBK 1024
#define DEG_EPB 2048          // edges per degree block (782 blocks)
#define PB_EDGES 4096         // edges per partition block (391 blocks)

__global__ __launch_bounds__(256) void degree_kernel(
    const int* __restrict__ src, const int* __restrict__ dst,
    int* __restrict__ cnt_out, int* __restrict__ cnt_in,
    int* __restrict__ bucket_cnt, int E) {
  __shared__ int hist[NBK];
  int tid = threadIdx.x;
#pragma unroll
  for (int i = 0; i < NBK / 256; ++i) hist[tid + i * 256] = 0;
  __syncthreads();
  int base = blockIdx.x * DEG_EPB + tid * 8;
  if (base + 8 <= E) {
#pragma unroll
    for (int i = 0; i < 2; ++i) {
      int4 s4 = ((const int4*)(src + base))[i];
      int4 d4 = ((const int4*)(dst + base))[i];
      int ss[4] = {s4.x, s4.y, s4.z, s4.w};
      int dd[4] = {d4.x, d4.y, d4.z, d4.w};
#pragma unroll
      for (int k = 0; k < 4; ++k) {
        atomicAdd(cnt_out + ss[k], 1);
        atomicAdd(cnt_in + dd[k], 1);
        atomicAdd(&hist[dd[k] >> BSHIFT], 1);
      }
    }
  } else {
    for (int j = 0; j < 8; ++j) {
      int e = base + j;
      if (e < E) {
        int s = src[e], d = dst[e];
        atomicAdd(cnt_out + s, 1);
        atomicAdd(cnt_in + d, 1);
        atomicAdd(&hist[d >> BSHIFT], 1);
      }
    }
  }
  __syncthreads();
#pragma unroll
  for (int i = 0; i < NBK / 256; ++i) {
    int b = tid + i * 256;
    if (hist[b]) atomicAdd(bucket_cnt + b, hist[b]);
  }
}

// h[n][o] = sum_k feat[n][k] * out_deg[n]^-0.5 * W[k][o]
__global__ __launch_bounds__(256, 2) void gemm_kernel(
    const float* __restrict__ feat, const float* __restrict__ W,
    const int* __restrict__ cnt_out, float* __restrict__ h, int N) {
  __shared__ float sW[IN_F * OUT_F];        // 32 KB
  __shared__ float sF[G_ROWS * G_KPAD];     // 36 KB
  __shared__ float sScale[G_ROWS];

  int tid = threadIdx.x;
  {
    const float4* W4 = (const float4*)W;
    float4* sW4 = (float4*)sW;
#pragma unroll
    for (int i = 0; i < 8; ++i) sW4[tid + i * 256] = W4[tid + i * 256];
  }
  int row0 = blockIdx.x * G_ROWS;
  {
    int gr = row0 + tid;
    float dg = (gr < N) ? (float)cnt_out[gr] : 1.f;
    sScale[tid] = dg < 1.f ? 1.f : rsqrtf(dg);
  }

  int tr = tid >> 3;
  int cg = (tid & 7) * 4;
  float acc[8][4];
#pragma unroll
  for (int i = 0; i < 8; ++i)
#pragma unroll
    for (int c = 0; c < 4; ++c) acc[i][c] = 0.f;

  for (int kt = 0; kt < IN_F; kt += G_KT) {
    __syncthreads();
#pragma unroll
    for (int i = 0; i < 8; ++i) {
      int idx = tid + i * 256;
      int r = idx >> 3;
      int kk = (idx & 7) * 4;
      int gr = row0 + r;
      float4 v = {0.f, 0.f, 0.f, 0.f};
      if (gr < N) {
        float s = sScale[r];
        v = *(const float4*)(feat + (size_t)gr * IN_F + kt + kk);
        v.x *= s; v.y *= s; v.z *= s; v.w *= s;
      }
      *(float4*)(sF + r * G_KPAD + kk) = v;
    }
    __syncthreads();

#pragma unroll
    for (int k4 = 0; k4 < G_KT; k4 += 4) {
      float4 a[8];
#pragma unroll
      for (int i = 0; i < 8; ++i)
        a[i] = *(const float4*)(sF + (tr + 32 * i) * G_KPAD + k4);
#pragma unroll
      for (int j = 0; j < 4; ++j) {
        float4 w = *(const float4*)(sW + (kt + k4 + j) * OUT_F + cg);
#pragma unroll
        for (int i = 0; i < 8; ++i) {
          float aj = (j == 0) ? a[i].x : (j == 1) ? a[i].y : (j == 2) ? a[i].z : a[i].w;
          acc[i][0] += aj * w.x;
          acc[i][1] += aj * w.y;
          acc[i][2] += aj * w.z;
          acc[i][3] += aj * w.w;
        }
      }
    }
  }

#pragma unroll
  for (int i = 0; i < 8; ++i) {
    int g = row0 + tr + 32 * i;
    if (g < N) {
      float4 o = {acc[i][0], acc[i][1], acc[i][2], acc[i][3]};
      *(float4*)(h + (size_t)g * OUT_F + cg) = o;
    }
  }
}

__global__ __launch_bounds__(1024) void bucket_scan_kernel(
    const int* __restrict__ bucket_cnt, int* __restrict__ bucket_base,
    int* __restrict__ bucket_cursor) {
  __shared__ int wsum[16];
  int tid = threadIdx.x;
  int v = bucket_cnt[tid];
  int x = v;
#pragma unroll
  for (int d = 1; d < 64; d <<= 1) {
    int y = __shfl_up(x, d, 64);
    if ((tid & 63) >= d) x += y;
  }
  if ((tid & 63) == 63) wsum[tid >> 6] = x;
  __syncthreads();
  int off = 0;
#pragma unroll
  for (int w = 0; w < 16; ++w)
    if (w < (tid >> 6)) off += wsum[w];
  int excl = off + x - v;
  bucket_base[tid] = excl;
  bucket_cursor[tid] = excl;
}

__global__ __launch_bounds__(1024) void partition_kernel(
    const int* __restrict__ src, const int* __restrict__ dst,
    int* __restrict__ bucket_cursor, unsigned* __restrict__ pairs, int E) {
  __shared__ unsigned sbuf[PB_EDGES];   // 16 KB
  __shared__ int hist[NBK];
  __shared__ int lbase[NBK + 1];
  __shared__ int gbase[NBK];
  __shared__ int wsum[16];

  int tid = threadIdx.x;
  hist[tid] = 0;
  __syncthreads();

  int e0 = blockIdx.x * PB_EDGES + tid * 4;
  int myb[4], myslot[4];
  unsigned mypk[4];
  if (e0 + 4 <= E) {
    int4 s0 = *(const int4*)(src + e0);
    int4 d0 = *(const int4*)(dst + e0);
    int ss[4] = {s0.x, s0.y, s0.z, s0.w};
    int dd[4] = {d0.x, d0.y, d0.z, d0.w};
#pragma unroll
    for (int j = 0; j < 4; ++j) {
      int b = dd[j] >> BSHIFT;
      myb[j] = b;
      mypk[j] = (unsigned)ss[j] | ((unsigned)(dd[j] & (BNODES - 1)) << 17);
      myslot[j] = atomicAdd(&hist[b], 1);
    }
  } else {
#pragma unroll
    for (int j = 0; j < 4; ++j) {
      int e = e0 + j;
      if (e < E) {
        int s = src[e], d = dst[e];
        int b = d >> BSHIFT;
        myb[j] = b;
        mypk[j] = (unsigned)s | ((unsigned)(d & (BNODES - 1)) << 17);
        myslot[j] = atomicAdd(&hist[b], 1);
      } else {
        myb[j] = -1;
      }
    }
  }
  __syncthreads();

  {
    int v = hist[tid];
    int x = v;
#pragma unroll
    for (int d = 1; d < 64; d <<= 1) {
      int y = __shfl_up(x, d, 64);
      if ((tid & 63) >= d) x += y;
    }
    if ((tid & 63) == 63) wsum[tid >> 6] = x;
    __syncthreads();
    int off = 0;
#pragma unroll
    for (int w = 0; w < 16; ++w)
      if (w < (tid >> 6)) off += wsum[w];
    lbase[tid] = off + x - v;
    if (tid == NBK - 1) lbase[NBK] = off + x;
    gbase[tid] = v ? atomicAdd(&bucket_cursor[tid], v) : 0;
  }
  __syncthreads();

#pragma unroll
  for (int j = 0; j < 4; ++j)
    if (myb[j] >= 0) sbuf[lbase[myb[j]] + myslot[j]] = mypk[j];
  __syncthreads();

  int total = lbase[NBK];
  int idx = tid * 4;
  if (idx < total) {
    int lo = 0, hi = NBK;
    while (hi - lo > 1) {
      int mid = (lo + hi) >> 1;
      if (lbase[mid] <= idx) lo = mid; else hi = mid;
    }
    int b = lo;
#pragma unroll
    for (int j = 0; j < 4; ++j, ++idx) {
      if (idx >= total) break;
      while (idx >= lbase[b + 1]) ++b;
      pairs[gbase[b] + (idx - lbase[b])] = sbuf[idx];
    }
  }
}

// One 1024-thread block per 128-node bucket; 32 groups x unroll 8.
__global__ __launch_bounds__(1024) void bucket_agg_kernel(
    const unsigned* __restrict__ pairs, const int* __restrict__ bucket_base,
    const int* __restrict__ bucket_cursor, const float* __restrict__ h,
    const int* __restrict__ cnt_in, const float* __restrict__ bias,
    float* __restrict__ out, int N) {
  __shared__ float acc[BNODES * OUT_F];   // 16 KB, bank = lane
  int tid = threadIdx.x;
  {
    float4 z = {0.f, 0.f, 0.f, 0.f};
    ((float4*)acc)[tid] = z;
  }
  __syncthreads();

  int b = blockIdx.x;
  int start = bucket_base[b];
  int end = bucket_cursor[b];
  int lane = tid & 31;
  int eg = tid >> 5;   // 32 groups

  for (int p = start + eg * 8; p < end; p += 256) {
    int m = end - p;   // >= 1
    unsigned pk[8];
#pragma unroll
    for (int j = 0; j < 8; ++j) pk[j] = (j < m) ? pairs[p + j] : 0u;
    float f[8];
#pragma unroll
    for (int j = 0; j < 8; ++j) f[j] = h[(size_t)(pk[j] & 0x1FFFF) * OUT_F + lane];
#pragma unroll
    for (int j = 0; j < 8; ++j)
      if (j < m) atomicAdd(&acc[(pk[j] >> 17) * OUT_F + lane], f[j]);
  }
  __syncthreads();

  int node0 = b << BSHIFT;
#pragma unroll
  for (int r = eg; r < BNODES; r += 32) {
    int node = node0 + r;
    if (node < N) {
      float dg = (float)cnt_in[node];
      float sc = dg < 1.f ? 1.f : rsqrtf(dg);
      float v = fmaf(acc[r * OUT_F + lane], sc, bias[lane]);
      out[(size_t)node * OUT_F + lane] = fmaxf(v, 0.f);
    }
  }
}

// ---- fallback (float-atomic) path ----
__global__ __launch_bounds__(256) void aggregate_kernel(
    const int* __restrict__ src, const int* __restrict__ dst,
    const float* __restrict__ h, float* __restrict__ out, int E) {
  int lane = threadIdx.x & 31;
  int e = (blockIdx.x * 256 + threadIdx.x) >> 5;
  if (e >= E) return;
  float v = h[(size_t)src[e] * OUT_F + lane];
  unsafeAtomicAdd(out + (size_t)dst[e] * OUT_F + lane, v);
}

__global__ __launch_bounds__(256) void finalize_kernel(
    float* __restrict__ out, const int* __restrict__ cnt_in,
    const float* __restrict__ bias, int N) {
  int idx = blockIdx.x * 256 + threadIdx.x;
  if (idx >= N * 8) return;
  int n = idx >> 3;
  int o = (idx & 7) * 4;
  float dg = (float)cnt_in[n];
  float s = dg < 1.f ? 1.f : rsqrtf(dg);
  float4 bv = *(const float4*)(bias + o);
  float4 v = ((const float4*)out)[idx];
  v.x = fmaxf(fmaf(v.x, s, bv.x), 0.f);
  v.y = fmaxf(fmaf(v.y, s, bv.y), 0.f);
  v.z = fmaxf(fmaf(v.z, s, bv.z), 0.f);
  v.w = fmaxf(fmaf(v.w, s, bv.w), 0.f);
  ((float4*)out)[idx] = v;
}

extern "C" void kernel_launch(void* const* d_in, const int* in_sizes, int n_in,
                              void* d_out, int out_size, void* d_ws, size_t ws_size,
                              hipStream_t stream) {
  const float* feat = (const float*)d_in[0];
  const int* src = (const int*)d_in[1];
  const int* dst = (const int*)d_in[2];
  const float* weight = (const float*)d_in[3];
  const float* bias = (const float*)d_in[4];
  float* out = (float*)d_out;

  int N = in_sizes[0] / IN_F;
  int E = in_sizes[1];
  int nb = (N + BNODES - 1) >> BSHIFT;

  float* h = (float*)d_ws;                        // N*32 floats
  int* cnt_out = (int*)(h + (size_t)N * OUT_F);   // N
  int* cnt_in = cnt_out + N;                      // N
  int* bucket_cnt = cnt_in + N;                   // NBK
  int* bucket_base = bucket_cnt + NBK;            // NBK+1
  int* bucket_cursor = bucket_base + NBK + 1;     // NBK
  unsigned* pairs = (unsigned*)(bucket_cursor + NBK);  // E

  size_t need = ((size_t)N * OUT_F + 2 * (size_t)N + (3 * NBK + 1) + (size_t)E) * 4;
  bool fast = (ws_size >= need) && (N <= (1 << 17)) && (nb <= NBK);

  if (fast) {
    hipMemsetAsync(cnt_out, 0, ((size_t)2 * N + NBK) * sizeof(int), stream);
    degree_kernel<<<(E + DEG_EPB - 1) / DEG_EPB, 256, 0, stream>>>(
        src, dst, cnt_out, cnt_in, bucket_cnt, E);
    gemm_kernel<<<(N + G_ROWS - 1) / G_ROWS, 256, 0, stream>>>(feat, weight, cnt_out, h, N);
    bucket_scan_kernel<<<1, 1024, 0, stream>>>(bucket_cnt, bucket_base, bucket_cursor);
    partition_kernel<<<(E + PB_EDGES - 1) / PB_EDGES, 1024, 0, stream>>>(
        src, dst, bucket_cursor, pairs, E);
    bucket_agg_kernel<<<nb, 1024, 0, stream>>>(
        pairs, bucket_base, bucket_cursor, h, cnt_in, bias, out, N);
  } else {
    hipMemsetAsync(cnt_out, 0, (size_t)2 * N * sizeof(int), stream);
    hipMemsetAsync(out, 0, (size_t)N * OUT_F * sizeof(float), stream);
    degree_kernel<<<(E + DEG_EPB - 1) / DEG_EPB, 256, 0, stream>>>(
        src, dst, cnt_out, cnt_in, bucket_cnt, E);
    gemm_kernel<<<(N + G_ROWS - 1) / G_ROWS, 256, 0, stream>>>(feat, weight, cnt_out, h, N);
    aggregate_kernel<<<(E + 7) / 8, 256, 0, stream>>>(src, dst, h, out, E);
    finalize_kernel<<<(N * 8 + 255) / 256, 256, 0, stream>>>(out, cnt_in, bias, N);
  }
}

// Round 6
// 417.333 us; speedup vs baseline: 1.6691x; 1.6691x over previous
//
#include <hip/hip_runtime.h>
#include <hip/hip_bf16.h>

// GCN layer: N=100000, E=1600000, IN=256, OUT=32, fp32.
// R5 lesson: bucket_agg was bound by per-edge 32-lane LDS f32 atomics
// (~2.5 cyc/lane RMW, per-CU serial pipe; invariant across occupancy).
// R6: counting-sort edges by dst inside each bucket (1 LDS int atomic/edge),
// then register-accumulate contiguous runs -> no f32 atomics at all.
//   1) degree_kernel: cnt_out[src]++, cnt_in[dst]++, per-block bucket hist
//   2) gemm_kernel:   h = (feat * out_deg^-0.5) @ W
//   3) bucket_scan:   exclusive scan of 1024 bucket counts
//   4) partition_kernel: LDS counting sort -> pairs[] grouped by dst-bucket
//      (packed u32: src[16:0] | dstlow[23:17]); coalesced segment flush
//   5) sort_agg_kernel: per bucket, counting-sort by dstlow in LDS, then
//      each 32-lane group walks node runs with register acc; fused epilogue
// Fallback: float-atomic aggregate if ws too small or N >= 2^17.

#define IN_F 256
#define OUT_F 32

// gemm tiling
#define G_ROWS 256
#define G_KT 32
#define G_KPAD 36

// buckets
#define BSHIFT 7
#define BNODES 128
#define NBK 1024
#define DEG_EPB 2048
#define PB_EDGES 4096
#define AGG_CAP 4096          // edges sorted per chunk (mean/bucket ~1562)

__global__ __launch_bounds__(256) void degree_kernel(
    const int* __restrict__ src, const int* __restrict__ dst,
    int* __restrict__ cnt_out, int* __restrict__ cnt_in,
    int* __restrict__ bucket_cnt, int E) {
  __shared__ int hist[NBK];
  int tid = threadIdx.x;
#pragma unroll
  for (int i = 0; i < NBK / 256; ++i) hist[tid + i * 256] = 0;
  __syncthreads();
  int base = blockIdx.x * DEG_EPB + tid * 8;
  if (base + 8 <= E) {
#pragma unroll
    for (int i = 0; i < 2; ++i) {
      int4 s4 = ((const int4*)(src + base))[i];
      int4 d4 = ((const int4*)(dst + base))[i];
      int ss[4] = {s4.x, s4.y, s4.z, s4.w};
      int dd[4] = {d4.x, d4.y, d4.z, d4.w};
#pragma unroll
      for (int k = 0; k < 4; ++k) {
        atomicAdd(cnt_out + ss[k], 1);
        atomicAdd(cnt_in + dd[k], 1);
        atomicAdd(&hist[dd[k] >> BSHIFT], 1);
      }
    }
  } else {
    for (int j = 0; j < 8; ++j) {
      int e = base + j;
      if (e < E) {
        int s = src[e], d = dst[e];
        atomicAdd(cnt_out + s, 1);
        atomicAdd(cnt_in + d, 1);
        atomicAdd(&hist[d >> BSHIFT], 1);
      }
    }
  }
  __syncthreads();
#pragma unroll
  for (int i = 0; i < NBK / 256; ++i) {
    int b = tid + i * 256;
    if (hist[b]) atomicAdd(bucket_cnt + b, hist[b]);
  }
}

// h[n][o] = sum_k feat[n][k] * out_deg[n]^-0.5 * W[k][o]
__global__ __launch_bounds__(256, 2) void gemm_kernel(
    const float* __restrict__ feat, const float* __restrict__ W,
    const int* __restrict__ cnt_out, float* __restrict__ h, int N) {
  __shared__ float sW[IN_F * OUT_F];        // 32 KB
  __shared__ float sF[G_ROWS * G_KPAD];     // 36 KB
  __shared__ float sScale[G_ROWS];

  int tid = threadIdx.x;
  {
    const float4* W4 = (const float4*)W;
    float4* sW4 = (float4*)sW;
#pragma unroll
    for (int i = 0; i < 8; ++i) sW4[tid + i * 256] = W4[tid + i * 256];
  }
  int row0 = blockIdx.x * G_ROWS;
  {
    int gr = row0 + tid;
    float dg = (gr < N) ? (float)cnt_out[gr] : 1.f;
    sScale[tid] = dg < 1.f ? 1.f : rsqrtf(dg);
  }

  int tr = tid >> 3;
  int cg = (tid & 7) * 4;
  float acc[8][4];
#pragma unroll
  for (int i = 0; i < 8; ++i)
#pragma unroll
    for (int c = 0; c < 4; ++c) acc[i][c] = 0.f;

  for (int kt = 0; kt < IN_F; kt += G_KT) {
    __syncthreads();
#pragma unroll
    for (int i = 0; i < 8; ++i) {
      int idx = tid + i * 256;
      int r = idx >> 3;
      int kk = (idx & 7) * 4;
      int gr = row0 + r;
      float4 v = {0.f, 0.f, 0.f, 0.f};
      if (gr < N) {
        float s = sScale[r];
        v = *(const float4*)(feat + (size_t)gr * IN_F + kt + kk);
        v.x *= s; v.y *= s; v.z *= s; v.w *= s;
      }
      *(float4*)(sF + r * G_KPAD + kk) = v;
    }
    __syncthreads();

#pragma unroll
    for (int k4 = 0; k4 < G_KT; k4 += 4) {
      float4 a[8];
#pragma unroll
      for (int i = 0; i < 8; ++i)
        a[i] = *(const float4*)(sF + (tr + 32 * i) * G_KPAD + k4);
#pragma unroll
      for (int j = 0; j < 4; ++j) {
        float4 w = *(const float4*)(sW + (kt + k4 + j) * OUT_F + cg);
#pragma unroll
        for (int i = 0; i < 8; ++i) {
          float aj = (j == 0) ? a[i].x : (j == 1) ? a[i].y : (j == 2) ? a[i].z : a[i].w;
          acc[i][0] += aj * w.x;
          acc[i][1] += aj * w.y;
          acc[i][2] += aj * w.z;
          acc[i][3] += aj * w.w;
        }
      }
    }
  }

#pragma unroll
  for (int i = 0; i < 8; ++i) {
    int g = row0 + tr + 32 * i;
    if (g < N) {
      float4 o = {acc[i][0], acc[i][1], acc[i][2], acc[i][3]};
      *(float4*)(h + (size_t)g * OUT_F + cg) = o;
    }
  }
}

__global__ __launch_bounds__(1024) void bucket_scan_kernel(
    const int* __restrict__ bucket_cnt, int* __restrict__ bucket_base,
    int* __restrict__ bucket_cursor) {
  __shared__ int wsum[16];
  int tid = threadIdx.x;
  int v = bucket_cnt[tid];
  int x = v;
#pragma unroll
  for (int d = 1; d < 64; d <<= 1) {
    int y = __shfl_up(x, d, 64);
    if ((tid & 63) >= d) x += y;
  }
  if ((tid & 63) == 63) wsum[tid >> 6] = x;
  __syncthreads();
  int off = 0;
#pragma unroll
  for (int w = 0; w < 16; ++w)
    if (w < (tid >> 6)) off += wsum[w];
  int excl = off + x - v;
  bucket_base[tid] = excl;
  bucket_cursor[tid] = excl;
}

__global__ __launch_bounds__(1024) void partition_kernel(
    const int* __restrict__ src, const int* __restrict__ dst,
    int* __restrict__ bucket_cursor, unsigned* __restrict__ pairs, int E) {
  __shared__ unsigned sbuf[PB_EDGES];   // 16 KB
  __shared__ int hist[NBK];
  __shared__ int lbase[NBK + 1];
  __shared__ int gbase[NBK];
  __shared__ int wsum[16];

  int tid = threadIdx.x;
  hist[tid] = 0;
  __syncthreads();

  int e0 = blockIdx.x * PB_EDGES + tid * 4;
  int myb[4], myslot[4];
  unsigned mypk[4];
  if (e0 + 4 <= E) {
    int4 s0 = *(const int4*)(src + e0);
    int4 d0 = *(const int4*)(dst + e0);
    int ss[4] = {s0.x, s0.y, s0.z, s0.w};
    int dd[4] = {d0.x, d0.y, d0.z, d0.w};
#pragma unroll
    for (int j = 0; j < 4; ++j) {
      int b = dd[j] >> BSHIFT;
      myb[j] = b;
      mypk[j] = (unsigned)ss[j] | ((unsigned)(dd[j] & (BNODES - 1)) << 17);
      myslot[j] = atomicAdd(&hist[b], 1);
    }
  } else {
#pragma unroll
    for (int j = 0; j < 4; ++j) {
      int e = e0 + j;
      if (e < E) {
        int s = src[e], d = dst[e];
        int b = d >> BSHIFT;
        myb[j] = b;
        mypk[j] = (unsigned)s | ((unsigned)(d & (BNODES - 1)) << 17);
        myslot[j] = atomicAdd(&hist[b], 1);
      } else {
        myb[j] = -1;
      }
    }
  }
  __syncthreads();

  {
    int v = hist[tid];
    int x = v;
#pragma unroll
    for (int d = 1; d < 64; d <<= 1) {
      int y = __shfl_up(x, d, 64);
      if ((tid & 63) >= d) x += y;
    }
    if ((tid & 63) == 63) wsum[tid >> 6] = x;
    __syncthreads();
    int off = 0;
#pragma unroll
    for (int w = 0; w < 16; ++w)
      if (w < (tid >> 6)) off += wsum[w];
    lbase[tid] = off + x - v;
    if (tid == NBK - 1) lbase[NBK] = off + x;
    gbase[tid] = v ? atomicAdd(&bucket_cursor[tid], v) : 0;
  }
  __syncthreads();

#pragma unroll
  for (int j = 0; j < 4; ++j)
    if (myb[j] >= 0) sbuf[lbase[myb[j]] + myslot[j]] = mypk[j];
  __syncthreads();

  int total = lbase[NBK];
  int idx = tid * 4;
  if (idx < total) {
    int lo = 0, hi = NBK;
    while (hi - lo > 1) {
      int mid = (lo + hi) >> 1;
      if (lbase[mid] <= idx) lo = mid; else hi = mid;
    }
    int b = lo;
#pragma unroll
    for (int j = 0; j < 4; ++j, ++idx) {
      if (idx >= total) break;
      while (idx >= lbase[b + 1]) ++b;
      pairs[gbase[b] + (idx - lbase[b])] = sbuf[idx];
    }
  }
}

// One 256-thread block per 128-node bucket. Counting-sort the bucket's edges
// by dstlow in LDS (int hist atomic, 1/edge), then 8 groups of 32 lanes walk
// contiguous runs: register accumulate, one plain store per node.
__global__ __launch_bounds__(256) void sort_agg_kernel(
    const unsigned* __restrict__ pairs, const int* __restrict__ bucket_base,
    const int* __restrict__ bucket_cursor, const float* __restrict__ h,
    const int* __restrict__ cnt_in, const float* __restrict__ bias,
    float* __restrict__ out, int N) {
  __shared__ unsigned spk[AGG_CAP];   // 16 KB
  __shared__ int hist[BNODES];
  __shared__ int rs[BNODES + 1];
  __shared__ int wsum2[4];

  int tid = threadIdx.x;
  int lane = tid & 31;
  int eg = tid >> 5;                  // 0..7; group eg owns nodes eg*16..+15
  int b = blockIdx.x;
  int start = bucket_base[b];
  int end = bucket_cursor[b];

  float acc[16];
#pragma unroll
  for (int t = 0; t < 16; ++t) acc[t] = 0.f;

  for (int chunk = start; chunk < end; chunk += AGG_CAP) {
    int cnt = min(end - chunk, AGG_CAP);
    if (tid < BNODES) hist[tid] = 0;
    __syncthreads();

    // stage edges in registers + LDS int histogram
    unsigned mypk[16];
    int myslot[16];
    int nmine = 0;
    for (int i = tid; i < cnt; i += 256) {
      unsigned pk = pairs[chunk + i];
      mypk[nmine] = pk;
      myslot[nmine] = atomicAdd(&hist[pk >> 17], 1);
      ++nmine;
    }
    __syncthreads();

    // exclusive scan hist[0..127] -> rs
    {
      int v = (tid < BNODES) ? hist[tid] : 0;
      int x = v;
#pragma unroll
      for (int d = 1; d < 64; d <<= 1) {
        int y = __shfl_up(x, d, 64);
        if ((tid & 63) >= d) x += y;
      }
      if ((tid & 63) == 63) wsum2[tid >> 6] = x;
      __syncthreads();
      int off = (tid >= 64 && tid < BNODES) ? wsum2[0] : 0;
      if (tid < BNODES) rs[tid] = off + x - v;
      if (tid == BNODES - 1) rs[BNODES] = off + x;
    }
    __syncthreads();

    // place into sorted order
    for (int i = 0; i < nmine; ++i) {
      unsigned pk = mypk[i];
      spk[rs[pk >> 17] + myslot[i]] = pk;
    }
    __syncthreads();

    // walk runs: group eg, nodes eg*16 + t
#pragma unroll 1
    for (int t = 0; t < 16; ++t) {
      int n = eg * 16 + t;
      int a = rs[n], bnd = rs[n + 1];
      float s = acc[t];
      int j = a;
      for (; j + 4 <= bnd; j += 4) {
        unsigned p0 = spk[j], p1 = spk[j + 1], p2 = spk[j + 2], p3 = spk[j + 3];
        float f0 = h[(size_t)(p0 & 0x1FFFF) * OUT_F + lane];
        float f1 = h[(size_t)(p1 & 0x1FFFF) * OUT_F + lane];
        float f2 = h[(size_t)(p2 & 0x1FFFF) * OUT_F + lane];
        float f3 = h[(size_t)(p3 & 0x1FFFF) * OUT_F + lane];
        s += f0; s += f1; s += f2; s += f3;
      }
      for (; j < bnd; ++j)
        s += h[(size_t)(spk[j] & 0x1FFFF) * OUT_F + lane];
      acc[t] = s;
    }
    __syncthreads();
  }

  // fused epilogue
  int node0 = b << BSHIFT;
#pragma unroll
  for (int t = 0; t < 16; ++t) {
    int node = node0 + eg * 16 + t;
    if (node < N) {
      float dg = (float)cnt_in[node];
      float sc = dg < 1.f ? 1.f : rsqrtf(dg);
      out[(size_t)node * OUT_F + lane] = fmaxf(fmaf(acc[t], sc, bias[lane]), 0.f);
    }
  }
}

// ---- fallback (float-atomic) path ----
__global__ __launch_bounds__(256) void aggregate_kernel(
    const int* __restrict__ src, const int* __restrict__ dst,
    const float* __restrict__ h, float* __restrict__ out, int E) {
  int lane = threadIdx.x & 31;
  int e = (blockIdx.x * 256 + threadIdx.x) >> 5;
  if (e >= E) return;
  float v = h[(size_t)src[e] * OUT_F + lane];
  unsafeAtomicAdd(out + (size_t)dst[e] * OUT_F + lane, v);
}

__global__ __launch_bounds__(256) void finalize_kernel(
    float* __restrict__ out, const int* __restrict__ cnt_in,
    const float* __restrict__ bias, int N) {
  int idx = blockIdx.x * 256 + threadIdx.x;
  if (idx >= N * 8) return;
  int n = idx >> 3;
  int o = (idx & 7) * 4;
  float dg = (float)cnt_in[n];
  float s = dg < 1.f ? 1.f : rsqrtf(dg);
  float4 bv = *(const float4*)(bias + o);
  float4 v = ((const float4*)out)[idx];
  v.x = fmaxf(fmaf(v.x, s, bv.x), 0.f);
  v.y = fmaxf(fmaf(v.y, s, bv.y), 0.f);
  v.z = fmaxf(fmaf(v.z, s, bv.z), 0.f);
  v.w = fmaxf(fmaf(v.w, s, bv.w), 0.f);
  ((float4*)out)[idx] = v;
}

extern "C" void kernel_launch(void* const* d_in, const int* in_sizes, int n_in,
                              void* d_out, int out_size, void* d_ws, size_t ws_size,
                              hipStream_t stream) {
  const float* feat = (const float*)d_in[0];
  const int* src = (const int*)d_in[1];
  const int* dst = (const int*)d_in[2];
  const float* weight = (const float*)d_in[3];
  const float* bias = (const float*)d_in[4];
  float* out = (float*)d_out;

  int N = in_sizes[0] / IN_F;
  int E = in_sizes[1];
  int nb = (N + BNODES - 1) >> BSHIFT;

  float* h = (float*)d_ws;                        // N*32 floats
  int* cnt_out = (int*)(h + (size_t)N * OUT_F);   // N
  int* cnt_in = cnt_out + N;                      // N
  int* bucket_cnt = cnt_in + N;                   // NBK
  int* bucket_base = bucket_cnt + NBK;            // NBK+1
  int* bucket_cursor = bucket_base + NBK + 1;     // NBK
  unsigned* pairs = (unsigned*)(bucket_cursor + NBK);  // E

  size_t need = ((size_t)N * OUT_F + 2 * (size_t)N + (3 * NBK + 1) + (size_t)E) * 4;
  bool fast = (ws_size >= need) && (N <= (1 << 17)) && (nb <= NBK);

  if (fast) {
    hipMemsetAsync(cnt_out, 0, ((size_t)2 * N + NBK) * sizeof(int), stream);
    degree_kernel<<<(E + DEG_EPB - 1) / DEG_EPB, 256, 0, stream>>>(
        src, dst, cnt_out, cnt_in, bucket_cnt, E);
    gemm_kernel<<<(N + G_ROWS - 1) / G_ROWS, 256, 0, stream>>>(feat, weight, cnt_out, h, N);
    bucket_scan_kernel<<<1, 1024, 0, stream>>>(bucket_cnt, bucket_base, bucket_cursor);
    partition_kernel<<<(E + PB_EDGES - 1) / PB_EDGES, 1024, 0, stream>>>(
        src, dst, bucket_cursor, pairs, E);
    sort_agg_kernel<<<nb, 256, 0, stream>>>(
        pairs, bucket_base, bucket_cursor, h, cnt_in, bias, out, N);
  } else {
    hipMemsetAsync(cnt_out, 0, (size_t)2 * N * sizeof(int), stream);
    hipMemsetAsync(out, 0, (size_t)N * OUT_F * sizeof(float), stream);
    degree_kernel<<<(E + DEG_EPB - 1) / DEG_EPB, 256, 0, stream>>>(
        src, dst, cnt_out, cnt_in, bucket_cnt, E);
    gemm_kernel<<<(N + G_ROWS - 1) / G_ROWS, 256, 0, stream>>>(feat, weight, cnt_out, h, N);
    aggregate_kernel<<<(E + 7) / 8, 256, 0, stream>>>(src, dst, h, out, E);
    finalize_kernel<<<(N * 8 + 255) / 256, 256, 0, stream>>>(out, cnt_in, bias, N);
  }
}

// Round 7
// 337.692 us; speedup vs baseline: 2.0628x; 1.2358x over previous
//
#include <hip/hip_runtime.h>
#include <hip/hip_bf16.h>

// GCN layer: N=100000, E=1600000, IN=256, OUT=32, fp32.
// R6 lesson: every device-scope global atomic costs ~32B fabric write
// (degree: 3.2M atomics = 102MB WRITE @142us). R7: ZERO global atomics.
// Radix-style precomputed offsets:
//   1) hist_kernel: per-block u16 histograms of src-buckets & dst-buckets
//      (plain stores into npb x 1024 matrices)
//   2) offset_kernel: column-scan matrices in place -> per-block flush
//      offsets + bucket base arrays (exclusive scans)
//   3) partition_src: LDS counting sort -> pairs_s (u8 srclow), offsets
//      precomputed, no cursor atomics
//   4) src_count: per src-bucket LDS histogram -> scale_out = rsqrt(deg)
//   5) gemm: h = (feat * scale_out) @ W
//   6) partition_dst: LDS counting sort -> pairs (u32 src|dstlow<<17)
//   7) sort_agg: per dst-bucket counting sort + register run accumulation;
//      in-degree from run lengths; fused rsqrt+bias+relu epilogue
// Fallback: float-atomic path if ws too small or N > 2^17.

#define IN_F 256
#define OUT_F 32

// gemm tiling
#define G_ROWS 256
#define G_KT 32
#define G_KPAD 36

// buckets / partition
#define BSHIFT 7
#define BNODES 128
#define NBK 1024
#define PB_EDGES 8192
#define AGG_CAP 4096

// ---------------- fast path ----------------

__global__ __launch_bounds__(1024) void hist_kernel(
    const int* __restrict__ src, const int* __restrict__ dst,
    unsigned short* __restrict__ mhistS, unsigned short* __restrict__ mhistD,
    int E) {
  __shared__ int hS[NBK], hD[NBK];
  int tid = threadIdx.x;
  hS[tid] = 0; hD[tid] = 0;
  __syncthreads();
  int e0 = blockIdx.x * PB_EDGES + tid * 8;
  if (e0 + 8 <= E) {
    int4 a0 = ((const int4*)(src + e0))[0], a1 = ((const int4*)(src + e0))[1];
    int4 b0 = ((const int4*)(dst + e0))[0], b1 = ((const int4*)(dst + e0))[1];
    int ss[8] = {a0.x, a0.y, a0.z, a0.w, a1.x, a1.y, a1.z, a1.w};
    int dd[8] = {b0.x, b0.y, b0.z, b0.w, b1.x, b1.y, b1.z, b1.w};
#pragma unroll
    for (int j = 0; j < 8; ++j) {
      atomicAdd(&hS[ss[j] >> BSHIFT], 1);
      atomicAdd(&hD[dd[j] >> BSHIFT], 1);
    }
  } else {
    for (int j = 0; j < 8; ++j) {
      int e = e0 + j;
      if (e < E) {
        atomicAdd(&hS[src[e] >> BSHIFT], 1);
        atomicAdd(&hD[dst[e] >> BSHIFT], 1);
      }
    }
  }
  __syncthreads();
  mhistS[blockIdx.x * NBK + tid] = (unsigned short)hS[tid];
  mhistD[blockIdx.x * NBK + tid] = (unsigned short)hD[tid];
}

// blockIdx 0 -> S, 1 -> D. Converts mhist counts to within-bucket per-block
// exclusive prefixes (u16, safe: uniform-random buckets total ~1.8K << 64K)
// and writes bucket_base[NBK+1] (u32 exclusive scan of bucket totals).
__global__ __launch_bounds__(1024) void offset_kernel(
    unsigned short* __restrict__ mhistS, unsigned short* __restrict__ mhistD,
    int* __restrict__ baseS, int* __restrict__ baseD, int npb) {
  __shared__ int wsum[16];
  unsigned short* mh = blockIdx.x ? mhistD : mhistS;
  int* bb = blockIdx.x ? baseD : baseS;
  int b = threadIdx.x;
  int run = 0;
  for (int blk = 0; blk < npb; ++blk) {
    int idx = blk * NBK + b;
    int c = mh[idx];
    mh[idx] = (unsigned short)run;
    run += c;
  }
  int v = run, x = run;
#pragma unroll
  for (int d = 1; d < 64; d <<= 1) {
    int y = __shfl_up(x, d, 64);
    if ((b & 63) >= d) x += y;
  }
  if ((b & 63) == 63) wsum[b >> 6] = x;
  __syncthreads();
  int off = 0;
#pragma unroll
  for (int w = 0; w < 16; ++w)
    if (w < (b >> 6)) off += wsum[w];
  bb[b] = off + x - v;
  if (b == NBK - 1) bb[NBK] = off + x;
}

__global__ __launch_bounds__(1024) void partition_src_kernel(
    const int* __restrict__ src, const unsigned short* __restrict__ mbaseS,
    const int* __restrict__ baseS, unsigned char* __restrict__ pairs_s, int E) {
  __shared__ unsigned char sbuf[PB_EDGES];   // 8 KB
  __shared__ int hist[NBK];
  __shared__ int lbase[NBK + 1];
  __shared__ int gbase[NBK];
  __shared__ int wsum[16];

  int tid = threadIdx.x;
  hist[tid] = 0;
  __syncthreads();

  int e0 = blockIdx.x * PB_EDGES + tid * 8;
  int myb[8], myslot[8];
  unsigned char mylow[8];
  if (e0 + 8 <= E) {
    int4 a0 = ((const int4*)(src + e0))[0], a1 = ((const int4*)(src + e0))[1];
    int ss[8] = {a0.x, a0.y, a0.z, a0.w, a1.x, a1.y, a1.z, a1.w};
#pragma unroll
    for (int j = 0; j < 8; ++j) {
      int b = ss[j] >> BSHIFT;
      myb[j] = b;
      mylow[j] = (unsigned char)(ss[j] & (BNODES - 1));
      myslot[j] = atomicAdd(&hist[b], 1);
    }
  } else {
#pragma unroll
    for (int j = 0; j < 8; ++j) {
      int e = e0 + j;
      if (e < E) {
        int s = src[e];
        int b = s >> BSHIFT;
        myb[j] = b;
        mylow[j] = (unsigned char)(s & (BNODES - 1));
        myslot[j] = atomicAdd(&hist[b], 1);
      } else {
        myb[j] = -1;
      }
    }
  }
  __syncthreads();

  {
    int v = hist[tid];
    int x = v;
#pragma unroll
    for (int d = 1; d < 64; d <<= 1) {
      int y = __shfl_up(x, d, 64);
      if ((tid & 63) >= d) x += y;
    }
    if ((tid & 63) == 63) wsum[tid >> 6] = x;
    __syncthreads();
    int off = 0;
#pragma unroll
    for (int w = 0; w < 16; ++w)
      if (w < (tid >> 6)) off += wsum[w];
    lbase[tid] = off + x - v;
    if (tid == NBK - 1) lbase[NBK] = off + x;
    gbase[tid] = baseS[tid] + (int)mbaseS[blockIdx.x * NBK + tid];
  }
  __syncthreads();

#pragma unroll
  for (int j = 0; j < 8; ++j)
    if (myb[j] >= 0) sbuf[lbase[myb[j]] + myslot[j]] = mylow[j];
  __syncthreads();

  int total = lbase[NBK];
  int idx = tid * 8;
  if (idx < total) {
    int lo = 0, hi = NBK;
    while (hi - lo > 1) {
      int mid = (lo + hi) >> 1;
      if (lbase[mid] <= idx) lo = mid; else hi = mid;
    }
    int b = lo;
#pragma unroll
    for (int j = 0; j < 8; ++j, ++idx) {
      if (idx >= total) break;
      while (idx >= lbase[b + 1]) ++b;
      pairs_s[gbase[b] + (idx - lbase[b])] = sbuf[idx];
    }
  }
}

__global__ __launch_bounds__(256) void src_count_kernel(
    const unsigned char* __restrict__ pairs_s, const int* __restrict__ baseS,
    float* __restrict__ scale_out, int N) {
  __shared__ int hist[BNODES];
  int tid = threadIdx.x;
  int b = blockIdx.x;
  if (tid < BNODES) hist[tid] = 0;
  __syncthreads();
  int s = baseS[b], e = baseS[b + 1];
  for (int i = s + tid; i < e; i += 256) atomicAdd(&hist[pairs_s[i]], 1);
  __syncthreads();
  if (tid < BNODES) {
    int node = (b << BSHIFT) + tid;
    if (node < N) {
      int c = hist[tid];
      scale_out[node] = (c < 1) ? 1.f : rsqrtf((float)c);
    }
  }
}

// h[n][o] = sum_k feat[n][k] * scale_out[n] * W[k][o]
__global__ __launch_bounds__(256, 2) void gemm_kernel(
    const float* __restrict__ feat, const float* __restrict__ W,
    const float* __restrict__ scale_out, float* __restrict__ h, int N) {
  __shared__ float sW[IN_F * OUT_F];        // 32 KB
  __shared__ float sF[G_ROWS * G_KPAD];     // 36 KB
  __shared__ float sScale[G_ROWS];

  int tid = threadIdx.x;
  {
    const float4* W4 = (const float4*)W;
    float4* sW4 = (float4*)sW;
#pragma unroll
    for (int i = 0; i < 8; ++i) sW4[tid + i * 256] = W4[tid + i * 256];
  }
  int row0 = blockIdx.x * G_ROWS;
  {
    int gr = row0 + tid;
    sScale[tid] = (gr < N) ? scale_out[gr] : 1.f;
  }

  int tr = tid >> 3;
  int cg = (tid & 7) * 4;
  float acc[8][4];
#pragma unroll
  for (int i = 0; i < 8; ++i)
#pragma unroll
    for (int c = 0; c < 4; ++c) acc[i][c] = 0.f;

  for (int kt = 0; kt < IN_F; kt += G_KT) {
    __syncthreads();
#pragma unroll
    for (int i = 0; i < 8; ++i) {
      int idx = tid + i * 256;
      int r = idx >> 3;
      int kk = (idx & 7) * 4;
      int gr = row0 + r;
      float4 v = {0.f, 0.f, 0.f, 0.f};
      if (gr < N) {
        float s = sScale[r];
        v = *(const float4*)(feat + (size_t)gr * IN_F + kt + kk);
        v.x *= s; v.y *= s; v.z *= s; v.w *= s;
      }
      *(float4*)(sF + r * G_KPAD + kk) = v;
    }
    __syncthreads();

#pragma unroll
    for (int k4 = 0; k4 < G_KT; k4 += 4) {
      float4 a[8];
#pragma unroll
      for (int i = 0; i < 8; ++i)
        a[i] = *(const float4*)(sF + (tr + 32 * i) * G_KPAD + k4);
#pragma unroll
      for (int j = 0; j < 4; ++j) {
        float4 w = *(const float4*)(sW + (kt + k4 + j) * OUT_F + cg);
#pragma unroll
        for (int i = 0; i < 8; ++i) {
          float aj = (j == 0) ? a[i].x : (j == 1) ? a[i].y : (j == 2) ? a[i].z : a[i].w;
          acc[i][0] += aj * w.x;
          acc[i][1] += aj * w.y;
          acc[i][2] += aj * w.z;
          acc[i][3] += aj * w.w;
        }
      }
    }
  }

#pragma unroll
  for (int i = 0; i < 8; ++i) {
    int g = row0 + tr + 32 * i;
    if (g < N) {
      float4 o = {acc[i][0], acc[i][1], acc[i][2], acc[i][3]};
      *(float4*)(h + (size_t)g * OUT_F + cg) = o;
    }
  }
}

__global__ __launch_bounds__(1024) void partition_dst_kernel(
    const int* __restrict__ src, const int* __restrict__ dst,
    const unsigned short* __restrict__ mbaseD, const int* __restrict__ baseD,
    unsigned* __restrict__ pairs, int E) {
  __shared__ unsigned sbuf[PB_EDGES];   // 32 KB
  __shared__ int hist[NBK];
  __shared__ int lbase[NBK + 1];
  __shared__ int gbase[NBK];
  __shared__ int wsum[16];

  int tid = threadIdx.x;
  hist[tid] = 0;
  __syncthreads();

  int e0 = blockIdx.x * PB_EDGES + tid * 8;
  int myb[8], myslot[8];
  unsigned mypk[8];
  if (e0 + 8 <= E) {
    int4 a0 = ((const int4*)(src + e0))[0], a1 = ((const int4*)(src + e0))[1];
    int4 b0 = ((const int4*)(dst + e0))[0], b1 = ((const int4*)(dst + e0))[1];
    int ss[8] = {a0.x, a0.y, a0.z, a0.w, a1.x, a1.y, a1.z, a1.w};
    int dd[8] = {b0.x, b0.y, b0.z, b0.w, b1.x, b1.y, b1.z, b1.w};
#pragma unroll
    for (int j = 0; j < 8; ++j) {
      int b = dd[j] >> BSHIFT;
      myb[j] = b;
      mypk[j] = (unsigned)ss[j] | ((unsigned)(dd[j] & (BNODES - 1)) << 17);
      myslot[j] = atomicAdd(&hist[b], 1);
    }
  } else {
#pragma unroll
    for (int j = 0; j < 8; ++j) {
      int e = e0 + j;
      if (e < E) {
        int s = src[e], d = dst[e];
        int b = d >> BSHIFT;
        myb[j] = b;
        mypk[j] = (unsigned)s | ((unsigned)(d & (BNODES - 1)) << 17);
        myslot[j] = atomicAdd(&hist[b], 1);
      } else {
        myb[j] = -1;
      }
    }
  }
  __syncthreads();

  {
    int v = hist[tid];
    int x = v;
#pragma unroll
    for (int d = 1; d < 64; d <<= 1) {
      int y = __shfl_up(x, d, 64);
      if ((tid & 63) >= d) x += y;
    }
    if ((tid & 63) == 63) wsum[tid >> 6] = x;
    __syncthreads();
    int off = 0;
#pragma unroll
    for (int w = 0; w < 16; ++w)
      if (w < (tid >> 6)) off += wsum[w];
    lbase[tid] = off + x - v;
    if (tid == NBK - 1) lbase[NBK] = off + x;
    gbase[tid] = baseD[tid] + (int)mbaseD[blockIdx.x * NBK + tid];
  }
  __syncthreads();

#pragma unroll
  for (int j = 0; j < 8; ++j)
    if (myb[j] >= 0) sbuf[lbase[myb[j]] + myslot[j]] = mypk[j];
  __syncthreads();

  int total = lbase[NBK];
  int idx = tid * 8;
  if (idx < total) {
    int lo = 0, hi = NBK;
    while (hi - lo > 1) {
      int mid = (lo + hi) >> 1;
      if (lbase[mid] <= idx) lo = mid; else hi = mid;
    }
    int b = lo;
#pragma unroll
    for (int j = 0; j < 8; ++j, ++idx) {
      if (idx >= total) break;
      while (idx >= lbase[b + 1]) ++b;
      pairs[gbase[b] + (idx - lbase[b])] = sbuf[idx];
    }
  }
}

// Per 128-node dst bucket: counting-sort by dstlow, register-accumulate runs.
// In-degree derived from run lengths (no cnt_in array).
__global__ __launch_bounds__(256) void sort_agg_kernel(
    const unsigned* __restrict__ pairs, const int* __restrict__ baseD,
    const float* __restrict__ h, const float* __restrict__ bias,
    float* __restrict__ out, int N) {
  __shared__ unsigned spk[AGG_CAP];   // 16 KB
  __shared__ int hist[BNODES];
  __shared__ int rs[BNODES + 1];
  __shared__ int wsum2[4];

  int tid = threadIdx.x;
  int lane = tid & 31;
  int eg = tid >> 5;
  int b = blockIdx.x;
  int start = baseD[b];
  int end = baseD[b + 1];

  float acc[16];
  int degc[16];
#pragma unroll
  for (int t = 0; t < 16; ++t) { acc[t] = 0.f; degc[t] = 0; }

  for (int chunk = start; chunk < end; chunk += AGG_CAP) {
    int cnt = min(end - chunk, AGG_CAP);
    if (tid < BNODES) hist[tid] = 0;
    __syncthreads();

    unsigned mypk[16];
    int myslot[16];
    int nmine = 0;
    for (int i = tid; i < cnt; i += 256) {
      unsigned pk = pairs[chunk + i];
      mypk[nmine] = pk;
      myslot[nmine] = atomicAdd(&hist[pk >> 17], 1);
      ++nmine;
    }
    __syncthreads();

    {
      int v = (tid < BNODES) ? hist[tid] : 0;
      int x = v;
#pragma unroll
      for (int d = 1; d < 64; d <<= 1) {
        int y = __shfl_up(x, d, 64);
        if ((tid & 63) >= d) x += y;
      }
      if ((tid & 63) == 63) wsum2[tid >> 6] = x;
      __syncthreads();
      int off = (tid >= 64 && tid < BNODES) ? wsum2[0] : 0;
      if (tid < BNODES) rs[tid] = off + x - v;
      if (tid == BNODES - 1) rs[BNODES] = off + x;
    }
    __syncthreads();

    for (int i = 0; i < nmine; ++i) {
      unsigned pk = mypk[i];
      spk[rs[pk >> 17] + myslot[i]] = pk;
    }
    __syncthreads();

#pragma unroll 1
    for (int t = 0; t < 16; ++t) {
      int n = eg * 16 + t;
      int a = rs[n], bnd = rs[n + 1];
      degc[t] += bnd - a;
      float s = acc[t];
      int j = a;
      for (; j + 4 <= bnd; j += 4) {
        unsigned p0 = spk[j], p1 = spk[j + 1], p2 = spk[j + 2], p3 = spk[j + 3];
        float f0 = h[(size_t)(p0 & 0x1FFFF) * OUT_F + lane];
        float f1 = h[(size_t)(p1 & 0x1FFFF) * OUT_F + lane];
        float f2 = h[(size_t)(p2 & 0x1FFFF) * OUT_F + lane];
        float f3 = h[(size_t)(p3 & 0x1FFFF) * OUT_F + lane];
        s += f0; s += f1; s += f2; s += f3;
      }
      for (; j < bnd; ++j)
        s += h[(size_t)(spk[j] & 0x1FFFF) * OUT_F + lane];
      acc[t] = s;
    }
    __syncthreads();
  }

  int node0 = b << BSHIFT;
#pragma unroll
  for (int t = 0; t < 16; ++t) {
    int node = node0 + eg * 16 + t;
    if (node < N) {
      float sc = degc[t] > 0 ? rsqrtf((float)degc[t]) : 1.f;
      out[(size_t)node * OUT_F + lane] = fmaxf(fmaf(acc[t], sc, bias[lane]), 0.f);
    }
  }
}

// ---------------- fallback (float-atomic) path ----------------
__global__ __launch_bounds__(256) void degree_kernel(
    const int* __restrict__ src, const int* __restrict__ dst,
    int* __restrict__ cnt_out, int* __restrict__ cnt_in, int E) {
  int i = blockIdx.x * 256 + threadIdx.x;
  if (i < E) {
    atomicAdd(cnt_out + src[i], 1);
    atomicAdd(cnt_in + dst[i], 1);
  }
}

__global__ __launch_bounds__(256) void cnt_to_scale_kernel(
    const int* __restrict__ cnt, float* __restrict__ scale, int N) {
  int i = blockIdx.x * 256 + threadIdx.x;
  if (i < N) {
    int c = cnt[i];
    scale[i] = (c < 1) ? 1.f : rsqrtf((float)c);
  }
}

__global__ __launch_bounds__(256) void aggregate_kernel(
    const int* __restrict__ src, const int* __restrict__ dst,
    const float* __restrict__ h, float* __restrict__ out, int E) {
  int lane = threadIdx.x & 31;
  int e = (blockIdx.x * 256 + threadIdx.x) >> 5;
  if (e >= E) return;
  float v = h[(size_t)src[e] * OUT_F + lane];
  unsafeAtomicAdd(out + (size_t)dst[e] * OUT_F + lane, v);
}

__global__ __launch_bounds__(256) void finalize_kernel(
    float* __restrict__ out, const int* __restrict__ cnt_in,
    const float* __restrict__ bias, int N) {
  int idx = blockIdx.x * 256 + threadIdx.x;
  if (idx >= N * 8) return;
  int n = idx >> 3;
  int o = (idx & 7) * 4;
  float dg = (float)cnt_in[n];
  float s = dg < 1.f ? 1.f : rsqrtf(dg);
  float4 bv = *(const float4*)(bias + o);
  float4 v = ((const float4*)out)[idx];
  v.x = fmaxf(fmaf(v.x, s, bv.x), 0.f);
  v.y = fmaxf(fmaf(v.y, s, bv.y), 0.f);
  v.z = fmaxf(fmaf(v.z, s, bv.z), 0.f);
  v.w = fmaxf(fmaf(v.w, s, bv.w), 0.f);
  ((float4*)out)[idx] = v;
}

extern "C" void kernel_launch(void* const* d_in, const int* in_sizes, int n_in,
                              void* d_out, int out_size, void* d_ws, size_t ws_size,
                              hipStream_t stream) {
  const float* feat = (const float*)d_in[0];
  const int* src = (const int*)d_in[1];
  const int* dst = (const int*)d_in[2];
  const float* weight = (const float*)d_in[3];
  const float* bias = (const float*)d_in[4];
  float* out = (float*)d_out;

  int N = in_sizes[0] / IN_F;
  int E = in_sizes[1];
  int nb = (N + BNODES - 1) >> BSHIFT;          // used buckets
  int npb = (E + PB_EDGES - 1) / PB_EDGES;      // partition/hist blocks

  // fast-path layout (elements unless noted)
  float* h = (float*)d_ws;                                   // N*32 f32
  unsigned* pairs = (unsigned*)(h + (size_t)N * OUT_F);      // E u32 (pairs_s u8 first)
  unsigned char* pairs_s = (unsigned char*)pairs;
  unsigned short* mhistS = (unsigned short*)(pairs + E);     // npb*NBK u16
  unsigned short* mhistD = mhistS + (size_t)npb * NBK;       // npb*NBK u16
  int* baseS = (int*)(mhistD + (size_t)npb * NBK);           // NBK+1
  int* baseD = baseS + NBK + 1;                              // NBK+1
  float* scale_out = (float*)(baseD + NBK + 1);              // N f32

  size_t need = ((size_t)N * OUT_F + (size_t)E + (size_t)N + 2 * (NBK + 1)) * 4 +
                (size_t)npb * NBK * 2 * 2;
  bool fast = (ws_size >= need) && (N <= (1 << 17)) && (nb <= NBK);

  if (fast) {
    hist_kernel<<<npb, 1024, 0, stream>>>(src, dst, mhistS, mhistD, E);
    offset_kernel<<<2, 1024, 0, stream>>>(mhistS, mhistD, baseS, baseD, npb);
    partition_src_kernel<<<npb, 1024, 0, stream>>>(src, mhistS, baseS, pairs_s, E);
    src_count_kernel<<<nb, 256, 0, stream>>>(pairs_s, baseS, scale_out, N);
    gemm_kernel<<<(N + G_ROWS - 1) / G_ROWS, 256, 0, stream>>>(
        feat, weight, scale_out, h, N);
    partition_dst_kernel<<<npb, 1024, 0, stream>>>(src, dst, mhistD, baseD, pairs, E);
    sort_agg_kernel<<<nb, 256, 0, stream>>>(pairs, baseD, h, bias, out, N);
  } else {
    int* cnt_out = (int*)(h + (size_t)N * OUT_F);
    int* cnt_in = cnt_out + N;
    float* scl = (float*)(cnt_in + N);
    hipMemsetAsync(cnt_out, 0, (size_t)2 * N * sizeof(int), stream);
    hipMemsetAsync(out, 0, (size_t)N * OUT_F * sizeof(float), stream);
    degree_kernel<<<(E + 255) / 256, 256, 0, stream>>>(src, dst, cnt_out, cnt_in, E);
    cnt_to_scale_kernel<<<(N + 255) / 256, 256, 0, stream>>>(cnt_out, scl, N);
    gemm_kernel<<<(N + G_ROWS - 1) / G_ROWS, 256, 0, stream>>>(feat, weight, scl, h, N);
    aggregate_kernel<<<(E + 7) / 8, 256, 0, stream>>>(src, dst, h, out, E);
    finalize_kernel<<<(N * 8 + 255) / 256, 256, 0, stream>>>(out, cnt_in, bias, N);
  }
}

// Round 8
// 329.697 us; speedup vs baseline: 2.1128x; 1.0242x over previous
//
#include <hip/hip_runtime.h>
#include <hip/hip_bf16.h>

// GCN layer: N=100000, E=1600000, IN=256, OUT=32, fp32.
// R7 lesson: gemm was grid-starved (391 blocks x 4 waves = ~6 waves/CU) and
// its stage->sync->compute loop exposed every staging latency (77us vs ~23us
// DS floor). R8: barrier-free gemm — feat streamed directly from global
// (8 rows x 4 cols per thread, 16 float4 in flight), W in LDS (32KB,
// conflict-free), degree-scale folded into epilogue. No k-loop barriers.
// Rest of the zero-global-atomic radix pipeline unchanged:
//   hist -> offset -> partition_src -> src_count -> gemm -> partition_dst
//   -> sort_agg (fused rsqrt+bias+relu).

#define IN_F 256
#define OUT_F 32

#define G_ROWS 256

// buckets / partition
#define BSHIFT 7
#define BNODES 128
#define NBK 1024
#define PB_EDGES 8192
#define AGG_CAP 4096

// ---------------- fast path ----------------

__global__ __launch_bounds__(1024) void hist_kernel(
    const int* __restrict__ src, const int* __restrict__ dst,
    unsigned short* __restrict__ mhistS, unsigned short* __restrict__ mhistD,
    int E) {
  __shared__ int hS[NBK], hD[NBK];
  int tid = threadIdx.x;
  hS[tid] = 0; hD[tid] = 0;
  __syncthreads();
  int e0 = blockIdx.x * PB_EDGES + tid * 8;
  if (e0 + 8 <= E) {
    int4 a0 = ((const int4*)(src + e0))[0], a1 = ((const int4*)(src + e0))[1];
    int4 b0 = ((const int4*)(dst + e0))[0], b1 = ((const int4*)(dst + e0))[1];
    int ss[8] = {a0.x, a0.y, a0.z, a0.w, a1.x, a1.y, a1.z, a1.w};
    int dd[8] = {b0.x, b0.y, b0.z, b0.w, b1.x, b1.y, b1.z, b1.w};
#pragma unroll
    for (int j = 0; j < 8; ++j) {
      atomicAdd(&hS[ss[j] >> BSHIFT], 1);
      atomicAdd(&hD[dd[j] >> BSHIFT], 1);
    }
  } else {
    for (int j = 0; j < 8; ++j) {
      int e = e0 + j * 1;
      if (e < E) {
        atomicAdd(&hS[src[e] >> BSHIFT], 1);
        atomicAdd(&hD[dst[e] >> BSHIFT], 1);
      }
    }
  }
  __syncthreads();
  mhistS[blockIdx.x * NBK + tid] = (unsigned short)hS[tid];
  mhistD[blockIdx.x * NBK + tid] = (unsigned short)hD[tid];
}

// blockIdx 0 -> S, 1 -> D. Converts mhist counts to within-bucket per-block
// exclusive prefixes and writes bucket base arrays.
__global__ __launch_bounds__(1024) void offset_kernel(
    unsigned short* __restrict__ mhistS, unsigned short* __restrict__ mhistD,
    int* __restrict__ baseS, int* __restrict__ baseD, int npb) {
  __shared__ int wsum[16];
  unsigned short* mh = blockIdx.x ? mhistD : mhistS;
  int* bb = blockIdx.x ? baseD : baseS;
  int b = threadIdx.x;
  int run = 0;
  for (int blk = 0; blk < npb; ++blk) {
    int idx = blk * NBK + b;
    int c = mh[idx];
    mh[idx] = (unsigned short)run;
    run += c;
  }
  int v = run, x = run;
#pragma unroll
  for (int d = 1; d < 64; d <<= 1) {
    int y = __shfl_up(x, d, 64);
    if ((b & 63) >= d) x += y;
  }
  if ((b & 63) == 63) wsum[b >> 6] = x;
  __syncthreads();
  int off = 0;
#pragma unroll
  for (int w = 0; w < 16; ++w)
    if (w < (b >> 6)) off += wsum[w];
  bb[b] = off + x - v;
  if (b == NBK - 1) bb[NBK] = off + x;
}

__global__ __launch_bounds__(1024) void partition_src_kernel(
    const int* __restrict__ src, const unsigned short* __restrict__ mbaseS,
    const int* __restrict__ baseS, unsigned char* __restrict__ pairs_s, int E) {
  __shared__ unsigned char sbuf[PB_EDGES];   // 8 KB
  __shared__ int hist[NBK];
  __shared__ int lbase[NBK + 1];
  __shared__ int gbase[NBK];
  __shared__ int wsum[16];

  int tid = threadIdx.x;
  hist[tid] = 0;
  __syncthreads();

  int e0 = blockIdx.x * PB_EDGES + tid * 8;
  int myb[8], myslot[8];
  unsigned char mylow[8];
  if (e0 + 8 <= E) {
    int4 a0 = ((const int4*)(src + e0))[0], a1 = ((const int4*)(src + e0))[1];
    int ss[8] = {a0.x, a0.y, a0.z, a0.w, a1.x, a1.y, a1.z, a1.w};
#pragma unroll
    for (int j = 0; j < 8; ++j) {
      int b = ss[j] >> BSHIFT;
      myb[j] = b;
      mylow[j] = (unsigned char)(ss[j] & (BNODES - 1));
      myslot[j] = atomicAdd(&hist[b], 1);
    }
  } else {
#pragma unroll
    for (int j = 0; j < 8; ++j) {
      int e = e0 + j;
      if (e < E) {
        int s = src[e];
        int b = s >> BSHIFT;
        myb[j] = b;
        mylow[j] = (unsigned char)(s & (BNODES - 1));
        myslot[j] = atomicAdd(&hist[b], 1);
      } else {
        myb[j] = -1;
      }
    }
  }
  __syncthreads();

  {
    int v = hist[tid];
    int x = v;
#pragma unroll
    for (int d = 1; d < 64; d <<= 1) {
      int y = __shfl_up(x, d, 64);
      if ((tid & 63) >= d) x += y;
    }
    if ((tid & 63) == 63) wsum[tid >> 6] = x;
    __syncthreads();
    int off = 0;
#pragma unroll
    for (int w = 0; w < 16; ++w)
      if (w < (tid >> 6)) off += wsum[w];
    lbase[tid] = off + x - v;
    if (tid == NBK - 1) lbase[NBK] = off + x;
    gbase[tid] = baseS[tid] + (int)mbaseS[blockIdx.x * NBK + tid];
  }
  __syncthreads();

#pragma unroll
  for (int j = 0; j < 8; ++j)
    if (myb[j] >= 0) sbuf[lbase[myb[j]] + myslot[j]] = mylow[j];
  __syncthreads();

  int total = lbase[NBK];
  int idx = tid * 8;
  if (idx < total) {
    int lo = 0, hi = NBK;
    while (hi - lo > 1) {
      int mid = (lo + hi) >> 1;
      if (lbase[mid] <= idx) lo = mid; else hi = mid;
    }
    int b = lo;
#pragma unroll
    for (int j = 0; j < 8; ++j, ++idx) {
      if (idx >= total) break;
      while (idx >= lbase[b + 1]) ++b;
      pairs_s[gbase[b] + (idx - lbase[b])] = sbuf[idx];
    }
  }
}

__global__ __launch_bounds__(256) void src_count_kernel(
    const unsigned char* __restrict__ pairs_s, const int* __restrict__ baseS,
    float* __restrict__ scale_out, int N) {
  __shared__ int hist[BNODES];
  int tid = threadIdx.x;
  int b = blockIdx.x;
  if (tid < BNODES) hist[tid] = 0;
  __syncthreads();
  int s = baseS[b], e = baseS[b + 1];
  for (int i = s + tid; i < e; i += 256) atomicAdd(&hist[pairs_s[i]], 1);
  __syncthreads();
  if (tid < BNODES) {
    int node = (b << BSHIFT) + tid;
    if (node < N) {
      int c = hist[tid];
      scale_out[node] = (c < 1) ? 1.f : rsqrtf((float)c);
    }
  }
}

// h[n][o] = scale_out[n] * sum_k feat[n][k] * W[k][o]
// Barrier-free: thread owns 8 rows (stride 32) x 4 cols; feat streamed
// directly from global (float4, 16 in flight); W resident in LDS.
__global__ __launch_bounds__(256) void gemm_kernel(
    const float* __restrict__ feat, const float* __restrict__ W,
    const float* __restrict__ scale_out, float* __restrict__ h, int N) {
  __shared__ float sW[IN_F * OUT_F];   // [k][o], 32 KB
  __shared__ float sScale[G_ROWS];

  int tid = threadIdx.x;
  {
    const float4* W4 = (const float4*)W;
    float4* sW4 = (float4*)sW;
#pragma unroll
    for (int i = 0; i < 8; ++i) sW4[tid + i * 256] = W4[tid + i * 256];
  }
  int row0 = blockIdx.x * G_ROWS;
  {
    int gr = row0 + tid;
    sScale[tid] = (gr < N) ? scale_out[gr] : 0.f;
  }
  __syncthreads();

  int tr = tid >> 3;          // 0..31
  int cg = (tid & 7) * 4;     // col group
  const float* fp[8];
  bool valid[8];
#pragma unroll
  for (int i = 0; i < 8; ++i) {
    int g = row0 + tr + 32 * i;
    valid[i] = (g < N);
    fp[i] = feat + (size_t)(valid[i] ? g : 0) * IN_F;
  }

  float acc[8][4];
#pragma unroll
  for (int i = 0; i < 8; ++i)
#pragma unroll
    for (int c = 0; c < 4; ++c) acc[i][c] = 0.f;

  for (int k = 0; k < IN_F; k += 8) {
    float4 a0[8], a1[8];
#pragma unroll
    for (int i = 0; i < 8; ++i) a0[i] = *(const float4*)(fp[i] + k);
#pragma unroll
    for (int i = 0; i < 8; ++i) a1[i] = *(const float4*)(fp[i] + k + 4);
#pragma unroll
    for (int j = 0; j < 4; ++j) {
      float4 w = *(const float4*)(sW + (k + j) * OUT_F + cg);
#pragma unroll
      for (int i = 0; i < 8; ++i) {
        float aj = (j == 0) ? a0[i].x : (j == 1) ? a0[i].y : (j == 2) ? a0[i].z : a0[i].w;
        acc[i][0] = fmaf(aj, w.x, acc[i][0]);
        acc[i][1] = fmaf(aj, w.y, acc[i][1]);
        acc[i][2] = fmaf(aj, w.z, acc[i][2]);
        acc[i][3] = fmaf(aj, w.w, acc[i][3]);
      }
    }
#pragma unroll
    for (int j = 0; j < 4; ++j) {
      float4 w = *(const float4*)(sW + (k + 4 + j) * OUT_F + cg);
#pragma unroll
      for (int i = 0; i < 8; ++i) {
        float aj = (j == 0) ? a1[i].x : (j == 1) ? a1[i].y : (j == 2) ? a1[i].z : a1[i].w;
        acc[i][0] = fmaf(aj, w.x, acc[i][0]);
        acc[i][1] = fmaf(aj, w.y, acc[i][1]);
        acc[i][2] = fmaf(aj, w.z, acc[i][2]);
        acc[i][3] = fmaf(aj, w.w, acc[i][3]);
      }
    }
  }

#pragma unroll
  for (int i = 0; i < 8; ++i) {
    int r = tr + 32 * i;
    if (valid[i]) {
      float s = sScale[r];
      float4 o = {acc[i][0] * s, acc[i][1] * s, acc[i][2] * s, acc[i][3] * s};
      *(float4*)(h + (size_t)(row0 + r) * OUT_F + cg) = o;
    }
  }
}

__global__ __launch_bounds__(1024) void partition_dst_kernel(
    const int* __restrict__ src, const int* __restrict__ dst,
    const unsigned short* __restrict__ mbaseD, const int* __restrict__ baseD,
    unsigned* __restrict__ pairs, int E) {
  __shared__ unsigned sbuf[PB_EDGES];   // 32 KB
  __shared__ int hist[NBK];
  __shared__ int lbase[NBK + 1];
  __shared__ int gbase[NBK];
  __shared__ int wsum[16];

  int tid = threadIdx.x;
  hist[tid] = 0;
  __syncthreads();

  int e0 = blockIdx.x * PB_EDGES + tid * 8;
  int myb[8], myslot[8];
  unsigned mypk[8];
  if (e0 + 8 <= E) {
    int4 a0 = ((const int4*)(src + e0))[0], a1 = ((const int4*)(src + e0))[1];
    int4 b0 = ((const int4*)(dst + e0))[0], b1 = ((const int4*)(dst + e0))[1];
    int ss[8] = {a0.x, a0.y, a0.z, a0.w, a1.x, a1.y, a1.z, a1.w};
    int dd[8] = {b0.x, b0.y, b0.z, b0.w, b1.x, b1.y, b1.z, b1.w};
#pragma unroll
    for (int j = 0; j < 8; ++j) {
      int b = dd[j] >> BSHIFT;
      myb[j] = b;
      mypk[j] = (unsigned)ss[j] | ((unsigned)(dd[j] & (BNODES - 1)) << 17);
      myslot[j] = atomicAdd(&hist[b], 1);
    }
  } else {
#pragma unroll
    for (int j = 0; j < 8; ++j) {
      int e = e0 + j;
      if (e < E) {
        int s = src[e], d = dst[e];
        int b = d >> BSHIFT;
        myb[j] = b;
        mypk[j] = (unsigned)s | ((unsigned)(d & (BNODES - 1)) << 17);
        myslot[j] = atomicAdd(&hist[b], 1);
      } else {
        myb[j] = -1;
      }
    }
  }
  __syncthreads();

  {
    int v = hist[tid];
    int x = v;
#pragma unroll
    for (int d = 1; d < 64; d <<= 1) {
      int y = __shfl_up(x, d, 64);
      if ((tid & 63) >= d) x += y;
    }
    if ((tid & 63) == 63) wsum[tid >> 6] = x;
    __syncthreads();
    int off = 0;
#pragma unroll
    for (int w = 0; w < 16; ++w)
      if (w < (tid >> 6)) off += wsum[w];
    lbase[tid] = off + x - v;
    if (tid == NBK - 1) lbase[NBK] = off + x;
    gbase[tid] = baseD[tid] + (int)mbaseD[blockIdx.x * NBK + tid];
  }
  __syncthreads();

#pragma unroll
  for (int j = 0; j < 8; ++j)
    if (myb[j] >= 0) sbuf[lbase[myb[j]] + myslot[j]] = mypk[j];
  __syncthreads();

  int total = lbase[NBK];
  int idx = tid * 8;
  if (idx < total) {
    int lo = 0, hi = NBK;
    while (hi - lo > 1) {
      int mid = (lo + hi) >> 1;
      if (lbase[mid] <= idx) lo = mid; else hi = mid;
    }
    int b = lo;
#pragma unroll
    for (int j = 0; j < 8; ++j, ++idx) {
      if (idx >= total) break;
      while (idx >= lbase[b + 1]) ++b;
      pairs[gbase[b] + (idx - lbase[b])] = sbuf[idx];
    }
  }
}

// Per 128-node dst bucket: counting-sort by dstlow, register-accumulate runs.
__global__ __launch_bounds__(256) void sort_agg_kernel(
    const unsigned* __restrict__ pairs, const int* __restrict__ baseD,
    const float* __restrict__ h, const float* __restrict__ bias,
    float* __restrict__ out, int N) {
  __shared__ unsigned spk[AGG_CAP];   // 16 KB
  __shared__ int hist[BNODES];
  __shared__ int rs[BNODES + 1];
  __shared__ int wsum2[4];

  int tid = threadIdx.x;
  int lane = tid & 31;
  int eg = tid >> 5;
  int b = blockIdx.x;
  int start = baseD[b];
  int end = baseD[b + 1];

  float acc[16];
  int degc[16];
#pragma unroll
  for (int t = 0; t < 16; ++t) { acc[t] = 0.f; degc[t] = 0; }

  for (int chunk = start; chunk < end; chunk += AGG_CAP) {
    int cnt = min(end - chunk, AGG_CAP);
    if (tid < BNODES) hist[tid] = 0;
    __syncthreads();

    unsigned mypk[16];
    int myslot[16];
    int nmine = 0;
    for (int i = tid; i < cnt; i += 256) {
      unsigned pk = pairs[chunk + i];
      mypk[nmine] = pk;
      myslot[nmine] = atomicAdd(&hist[pk >> 17], 1);
      ++nmine;
    }
    __syncthreads();

    {
      int v = (tid < BNODES) ? hist[tid] : 0;
      int x = v;
#pragma unroll
      for (int d = 1; d < 64; d <<= 1) {
        int y = __shfl_up(x, d, 64);
        if ((tid & 63) >= d) x += y;
      }
      if ((tid & 63) == 63) wsum2[tid >> 6] = x;
      __syncthreads();
      int off = (tid >= 64 && tid < BNODES) ? wsum2[0] : 0;
      if (tid < BNODES) rs[tid] = off + x - v;
      if (tid == BNODES - 1) rs[BNODES] = off + x;
    }
    __syncthreads();

    for (int i = 0; i < nmine; ++i) {
      unsigned pk = mypk[i];
      spk[rs[pk >> 17] + myslot[i]] = pk;
    }
    __syncthreads();

#pragma unroll 1
    for (int t = 0; t < 16; ++t) {
      int n = eg * 16 + t;
      int a = rs[n], bnd = rs[n + 1];
      degc[t] += bnd - a;
      float s = acc[t];
      int j = a;
      for (; j + 4 <= bnd; j += 4) {
        unsigned p0 = spk[j], p1 = spk[j + 1], p2 = spk[j + 2], p3 = spk[j + 3];
        float f0 = h[(size_t)(p0 & 0x1FFFF) * OUT_F + lane];
        float f1 = h[(size_t)(p1 & 0x1FFFF) * OUT_F + lane];
        float f2 = h[(size_t)(p2 & 0x1FFFF) * OUT_F + lane];
        float f3 = h[(size_t)(p3 & 0x1FFFF) * OUT_F + lane];
        s += f0; s += f1; s += f2; s += f3;
      }
      for (; j < bnd; ++j)
        s += h[(size_t)(spk[j] & 0x1FFFF) * OUT_F + lane];
      acc[t] = s;
    }
    __syncthreads();
  }

  int node0 = b << BSHIFT;
#pragma unroll
  for (int t = 0; t < 16; ++t) {
    int node = node0 + eg * 16 + t;
    if (node < N) {
      float sc = degc[t] > 0 ? rsqrtf((float)degc[t]) : 1.f;
      out[(size_t)node * OUT_F + lane] = fmaxf(fmaf(acc[t], sc, bias[lane]), 0.f);
    }
  }
}

// ---------------- fallback (float-atomic) path ----------------
__global__ __launch_bounds__(256) void degree_kernel(
    const int* __restrict__ src, const int* __restrict__ dst,
    int* __restrict__ cnt_out, int* __restrict__ cnt_in, int E) {
  int i = blockIdx.x * 256 + threadIdx.x;
  if (i < E) {
    atomicAdd(cnt_out + src[i], 1);
    atomicAdd(cnt_in + dst[i], 1);
  }
}

__global__ __launch_bounds__(256) void cnt_to_scale_kernel(
    const int* __restrict__ cnt, float* __restrict__ scale, int N) {
  int i = blockIdx.x * 256 + threadIdx.x;
  if (i < N) {
    int c = cnt[i];
    scale[i] = (c < 1) ? 1.f : rsqrtf((float)c);
  }
}

__global__ __launch_bounds__(256) void aggregate_kernel(
    const int* __restrict__ src, const int* __restrict__ dst,
    const float* __restrict__ h, float* __restrict__ out, int E) {
  int lane = threadIdx.x & 31;
  int e = (blockIdx.x * 256 + threadIdx.x) >> 5;
  if (e >= E) return;
  float v = h[(size_t)src[e] * OUT_F + lane];
  unsafeAtomicAdd(out + (size_t)dst[e] * OUT_F + lane, v);
}

__global__ __launch_bounds__(256) void finalize_kernel(
    float* __restrict__ out, const int* __restrict__ cnt_in,
    const float* __restrict__ bias, int N) {
  int idx = blockIdx.x * 256 + threadIdx.x;
  if (idx >= N * 8) return;
  int n = idx >> 3;
  int o = (idx & 7) * 4;
  float dg = (float)cnt_in[n];
  float s = dg < 1.f ? 1.f : rsqrtf(dg);
  float4 bv = *(const float4*)(bias + o);
  float4 v = ((const float4*)out)[idx];
  v.x = fmaxf(fmaf(v.x, s, bv.x), 0.f);
  v.y = fmaxf(fmaf(v.y, s, bv.y), 0.f);
  v.z = fmaxf(fmaf(v.z, s, bv.z), 0.f);
  v.w = fmaxf(fmaf(v.w, s, bv.w), 0.f);
  ((float4*)out)[idx] = v;
}

extern "C" void kernel_launch(void* const* d_in, const int* in_sizes, int n_in,
                              void* d_out, int out_size, void* d_ws, size_t ws_size,
                              hipStream_t stream) {
  const float* feat = (const float*)d_in[0];
  const int* src = (const int*)d_in[1];
  const int* dst = (const int*)d_in[2];
  const float* weight = (const float*)d_in[3];
  const float* bias = (const float*)d_in[4];
  float* out = (float*)d_out;

  int N = in_sizes[0] / IN_F;
  int E = in_sizes[1];
  int nb = (N + BNODES - 1) >> BSHIFT;
  int npb = (E + PB_EDGES - 1) / PB_EDGES;

  float* h = (float*)d_ws;                                   // N*32 f32
  unsigned* pairs = (unsigned*)(h + (size_t)N * OUT_F);      // E u32
  unsigned char* pairs_s = (unsigned char*)pairs;
  unsigned short* mhistS = (unsigned short*)(pairs + E);     // npb*NBK u16
  unsigned short* mhistD = mhistS + (size_t)npb * NBK;       // npb*NBK u16
  int* baseS = (int*)(mhistD + (size_t)npb * NBK);           // NBK+1
  int* baseD = baseS + NBK + 1;                              // NBK+1
  float* scale_out = (float*)(baseD + NBK + 1);              // N f32

  size_t need = ((size_t)N * OUT_F + (size_t)E + (size_t)N + 2 * (NBK + 1)) * 4 +
                (size_t)npb * NBK * 2 * 2;
  bool fast = (ws_size >= need) && (N <= (1 << 17)) && (nb <= NBK);

  if (fast) {
    hist_kernel<<<npb, 1024, 0, stream>>>(src, dst, mhistS, mhistD, E);
    offset_kernel<<<2, 1024, 0, stream>>>(mhistS, mhistD, baseS, baseD, npb);
    partition_src_kernel<<<npb, 1024, 0, stream>>>(src, mhistS, baseS, pairs_s, E);
    src_count_kernel<<<nb, 256, 0, stream>>>(pairs_s, baseS, scale_out, N);
    gemm_kernel<<<(N + G_ROWS - 1) / G_ROWS, 256, 0, stream>>>(
        feat, weight, scale_out, h, N);
    partition_dst_kernel<<<npb, 1024, 0, stream>>>(src, dst, mhistD, baseD, pairs, E);
    sort_agg_kernel<<<nb, 256, 0, stream>>>(pairs, baseD, h, bias, out, N);
  } else {
    int* cnt_out = (int*)(h + (size_t)N * OUT_F);
    int* cnt_in = cnt_out + N;
    float* scl = (float*)(cnt_in + N);
    hipMemsetAsync(cnt_out, 0, (size_t)2 * N * sizeof(int), stream);
    hipMemsetAsync(out, 0, (size_t)N * OUT_F * sizeof(float), stream);
    degree_kernel<<<(E + 255) / 256, 256, 0, stream>>>(src, dst, cnt_out, cnt_in, E);
    cnt_to_scale_kernel<<<(N + 255) / 256, 256, 0, stream>>>(cnt_out, scl, N);
    gemm_kernel<<<(N + G_ROWS - 1) / G_ROWS, 256, 0, stream>>>(feat, weight, scl, h, N);
    aggregate_kernel<<<(E + 7) / 8, 256, 0, stream>>>(src, dst, h, out, E);
    finalize_kernel<<<(N * 8 + 255) / 256, 256, 0, stream>>>(out, cnt_in, bias, N);
  }
}